// Round 11
// baseline (1177.359 us; speedup 1.0000x reference)
//
#include <hip/hip_runtime.h>
#include <hip/hip_bf16.h>

#define TT 32
#define DD 128
#define HH 256
#define VV 32000
#define ZZ 256
#define NTL 50            // n-slabs for V-GEMM (50 x 640 = 32000)
#define NBLK7 8           // rnn blocks (8 j-slices, both variants per block)
#define GHLP7 200         // ghl row pitch in f16 (192 + 8 pad)

typedef __attribute__((ext_vector_type(8))) short bf16x8;
typedef __attribute__((ext_vector_type(4))) float f32x4;
typedef __attribute__((ext_vector_type(8))) _Float16 f16x8;

static __device__ inline unsigned short f2bf(float x) {
    __hip_bfloat16 h = __float2bfloat16(x);
    return *(unsigned short*)&h;
}

static __device__ inline unsigned long long pack4h(_Float16 a, _Float16 b,
                                                   _Float16 c, _Float16 d) {
    union { _Float16 h[4]; unsigned long long u; } x;
    x.h[0] = a; x.h[1] = b; x.h[2] = c; x.h[3] = d;
    return x.u;
}

// ---------------- edges canonicalizer (bool-vs-int32 layout detect) ----------------
__global__ void edge_canon_k(const unsigned char* __restrict__ eb,
                             unsigned char* __restrict__ canon)
{
    __shared__ int flag;
    if (threadIdx.x == 0) flag = 0;
    __syncthreads();
    int acc = 0;
    for (int i = threadIdx.x; i < TT * DD; i += 256)
        if (i & 3) acc |= eb[i];
    if (acc) atomicOr(&flag, 1);
    __syncthreads();
    const bool is_i32 = (flag == 0);
    for (int i = threadIdx.x; i < TT * DD; i += 256)
        canon[i] = is_i32 ? eb[4 * (size_t)i] : eb[i];
}

// ---------------- pack f32 [nrow16*16][256] -> fragment-linear bf16 ----------------
__global__ __launch_bounds__(256) void pack_frag(
    const float* __restrict__ src, __hip_bfloat16* __restrict__ dst, int nchunks_total)
{
    int i = blockIdx.x * 256 + threadIdx.x;
    if (i >= nchunks_total) return;
    int lane = i & 63, ks = (i >> 6) & 7, j = i >> 9;
    int g = lane >> 4, c = lane & 15;
    const float* s = src + (size_t)(j * 16 + c) * HH + ks * 32 + g * 8;
    float4 v0 = *(const float4*)s;
    float4 v1 = *(const float4*)(s + 4);
    bf16x8 o;
    o[0] = (short)f2bf(v0.x); o[1] = (short)f2bf(v0.y);
    o[2] = (short)f2bf(v0.z); o[3] = (short)f2bf(v0.w);
    o[4] = (short)f2bf(v1.x); o[5] = (short)f2bf(v1.y);
    o[6] = (short)f2bf(v1.z); o[7] = (short)f2bf(v1.w);
    *(bf16x8*)(dst + (size_t)i * 8) = o;
}

// ---------------- pack Whh f32 [768][256] -> rnn B-frag layout, one slot ----------------
__global__ __launch_bounds__(256) void pack_wrnn(
    const float* __restrict__ src, _Float16* __restrict__ dst)
{
    int i = blockIdx.x * 256 + threadIdx.x;   // 24576
    if (i >= 24576) return;
    int lane = i & 63;
    int t2 = i >> 6;
    int ks = t2 & 7;
    int t3 = t2 >> 3;
    int tt = t3 % 6;
    int j8 = t3 / 6;
    int g = lane >> 4, c = lane & 15;
    int jg2 = tt / 3, gt = tt % 3;
    int srow = gt * 256 + j8 * 32 + jg2 * 16 + c;
    int scol = ks * 32 + g * 8;
    const float* s = src + (size_t)srow * HH + scol;
    float4 v0 = *(const float4*)s;
    float4 v1 = *(const float4*)(s + 4);
    f16x8 o;
    o[0] = (_Float16)v0.x; o[1] = (_Float16)v0.y;
    o[2] = (_Float16)v0.z; o[3] = (_Float16)v0.w;
    o[4] = (_Float16)v1.x; o[5] = (_Float16)v1.y;
    o[6] = (_Float16)v1.z; o[7] = (_Float16)v1.w;
    *(f16x8*)(dst + (size_t)i * 8) = o;
}

// ---------------- gather emb rows by token -> packed fragment A [4096][256] ----------------
__global__ __launch_bounds__(256) void gather_pack(
    const int* __restrict__ nodes, const float* __restrict__ emb,
    __hip_bfloat16* __restrict__ dst)
{
    int i = blockIdx.x * 256 + threadIdx.x;      // 131072 chunks
    int lane = i & 63, ks = (i >> 6) & 7, j = i >> 9;
    int g = lane >> 4, c = lane & 15;
    int row = j * 16 + c;
    int tok = nodes[row];
    const float* s = emb + (size_t)tok * HH + ks * 32 + g * 8;
    float4 v0 = *(const float4*)s;
    float4 v1 = *(const float4*)(s + 4);
    bf16x8 o;
    o[0] = (short)f2bf(v0.x); o[1] = (short)f2bf(v0.y);
    o[2] = (short)f2bf(v0.z); o[3] = (short)f2bf(v0.w);
    o[4] = (short)f2bf(v1.x); o[5] = (short)f2bf(v1.y);
    o[6] = (short)f2bf(v1.z); o[7] = (short)f2bf(v1.w);
    *(bf16x8*)(dst + (size_t)i * 8) = o;
}

// ---------------- transpose 256x256 f32 (latent weights) ----------------
__global__ __launch_bounds__(256) void pack_lat_t(
    const float* __restrict__ src, float* __restrict__ dst)
{
    int i = blockIdx.x * 256 + threadIdx.x;   // 65536
    int j = i & 255, k = i >> 8;
    dst[(size_t)k * 256 + j] = src[(size_t)j * 256 + k];
}

// ============ register-stationary GEMM, packed operands ============
template<bool WRITE_C, bool HAS_BIAS, bool LSE_PARTIAL, bool LSE_SUB>
__global__ __launch_bounds__(256, 4) void gemm_rs(
    const __hip_bfloat16* __restrict__ A,
    const __hip_bfloat16* __restrict__ B,
    int ldc, int nchunks, int ntiles,
    const float* __restrict__ bias,
    const float* __restrict__ lse,
    float* __restrict__ C,
    float* __restrict__ pm, float* __restrict__ ps)
{
    __shared__ float lds_st[WRITE_C ? (4 * 16 * 68) : 1];

    const int tid  = threadIdx.x;
    const int w    = tid >> 6;
    const int lane = tid & 63;
    const int g    = lane >> 4;
    const int c    = lane & 15;
    const int m0   = blockIdx.x * 64;
    const int row16 = m0 + w * 16;
    const int n0   = blockIdx.y * (nchunks * 64);
    const int jb0  = n0 >> 4;

    bf16x8 a[8];
    {
        const __hip_bfloat16* ap = A + (((size_t)(row16 >> 4) * 8) * 64 + lane) * 8;
#pragma unroll
        for (int ks = 0; ks < 8; ++ks) a[ks] = *(const bf16x8*)(ap + ks * 512);
    }

    float mrun[4], srun[4];
#pragma unroll
    for (int r = 0; r < 4; ++r) { mrun[r] = -3.0e38f; srun[r] = 0.f; }

    float lsev[4];
    if (LSE_SUB) {
#pragma unroll
        for (int r = 0; r < 4; ++r) lsev[r] = lse[row16 + 4 * g + r];
    }

    for (int nc = 0; nc < nchunks; ++nc) {
        const int nb = n0 + nc * 64;
        const __hip_bfloat16* bp = B + (((size_t)(jb0 + nc * 4) * 8) * 64 + lane) * 8;

        f32x4 acc[4];
#pragma unroll
        for (int nf = 0; nf < 4; ++nf) acc[nf] = (f32x4){0.f, 0.f, 0.f, 0.f};

#pragma unroll
        for (int ks = 0; ks < 8; ++ks) {
            bf16x8 b0 = *(const bf16x8*)(bp + (0 * 8 + ks) * 512);
            bf16x8 b1 = *(const bf16x8*)(bp + (1 * 8 + ks) * 512);
            bf16x8 b2 = *(const bf16x8*)(bp + (2 * 8 + ks) * 512);
            bf16x8 b3 = *(const bf16x8*)(bp + (3 * 8 + ks) * 512);
            acc[0] = __builtin_amdgcn_mfma_f32_16x16x32_bf16(a[ks], b0, acc[0], 0, 0, 0);
            acc[1] = __builtin_amdgcn_mfma_f32_16x16x32_bf16(a[ks], b1, acc[1], 0, 0, 0);
            acc[2] = __builtin_amdgcn_mfma_f32_16x16x32_bf16(a[ks], b2, acc[2], 0, 0, 0);
            acc[3] = __builtin_amdgcn_mfma_f32_16x16x32_bf16(a[ks], b3, acc[3], 0, 0, 0);
        }

        float bv[4] = {0.f, 0.f, 0.f, 0.f};
        if (HAS_BIAS) {
#pragma unroll
            for (int nf = 0; nf < 4; ++nf) bv[nf] = bias[nb + nf * 16 + c];
        }

        if (LSE_PARTIAL) {
#pragma unroll
            for (int r = 0; r < 4; ++r) {
                float l0 = acc[0][r] + bv[0];
                float l1 = acc[1][r] + bv[1];
                float l2 = acc[2][r] + bv[2];
                float l3 = acc[3][r] + bv[3];
                float mc = fmaxf(fmaxf(l0, l1), fmaxf(l2, l3));
                float mn = fmaxf(mrun[r], mc);
                srun[r] = srun[r] * __expf(mrun[r] - mn)
                        + __expf(l0 - mn) + __expf(l1 - mn)
                        + __expf(l2 - mn) + __expf(l3 - mn);
                mrun[r] = mn;
            }
        }

        if (WRITE_C) {
            const int base = w * (16 * 68);
#pragma unroll
            for (int nf = 0; nf < 4; ++nf)
#pragma unroll
                for (int r = 0; r < 4; ++r) {
                    float v = acc[nf][r] + bv[nf];
                    if (LSE_SUB) v -= lsev[r];
                    lds_st[base + (4 * g + r) * 68 + nf * 16 + c] = v;
                }
#pragma unroll
            for (int i = 0; i < 4; ++i) {
                int lr = i * 4 + g;
                float4 v = *(const float4*)&lds_st[base + lr * 68 + c * 4];
                *(float4*)(C + (size_t)(row16 + lr) * ldc + nb + c * 4) = v;
            }
        }
    }

    if (LSE_PARTIAL) {
#pragma unroll
        for (int r = 0; r < 4; ++r) {
            float m = mrun[r], s = srun[r];
#pragma unroll
            for (int mk = 1; mk <= 8; mk <<= 1) {
                float m2 = __shfl_xor(m, mk);
                float s2 = __shfl_xor(s, mk);
                float mn = fmaxf(m, m2);
                s = s * __expf(m - mn) + s2 * __expf(m2 - mn);
                m = mn;
            }
            if (c == 0) {
                int row = row16 + 4 * g + r;
                pm[(size_t)row * ntiles + blockIdx.y] = m;
                ps[(size_t)row * ntiles + blockIdx.y] = s;
            }
        }
    }
}

// ============ fused recurrence v7: 8 both-variant j-slice blocks, no staging ============
// 8 blocks x 512 thr (8 waves = 4 dq x 2 vv). Block j8 holds BOTH variants'
// 32-col gate-triple weight slices in LDS (96KB). Per step: MFMA both variants
// (A-frags loaded straight from the previous write-once xh slot -> registers),
// acc -> ghl, balanced gate (per-d variant select from ghl, no divergence),
// 8B agent stores to slot bi, 8-flag barrier. No LDS h staging at all.
__global__ __launch_bounds__(512) void rnn_fused7(
    const unsigned char* __restrict__ ecan,
    const float* __restrict__ gi,          // [4096][3072]
    const _Float16* __restrict__ Wr,       // [4 slots][8 j8][6 tt][8 ks][64][8]
    const float* __restrict__ ecbih, const float* __restrict__ ecbhh,
    const float* __restrict__ esbih, const float* __restrict__ esbhh,
    const float* __restrict__ dcbih, const float* __restrict__ dcbhh,
    const float* __restrict__ dsbih, const float* __restrict__ dsbhh,
    const float* __restrict__ WmT, const float* __restrict__ WlT,
    const float* __restrict__ WhT,
    const float* __restrict__ b_mean, const float* __restrict__ b_logv,
    const float* __restrict__ b_l2h,
    const float* __restrict__ enc_init, const float* __restrict__ eps,
    float* __restrict__ out_mean, float* __restrict__ out_logv,
    float* __restrict__ out_z,
    __hip_bfloat16* __restrict__ outs_pk,
    _Float16* __restrict__ xh,             // [65][128][256] f16, write-once slots
    int* __restrict__ flags)               // [8]
{
    __shared__ _Float16 wlds[2][3072 * 8];      // 96K: both variants' slices
    __shared__ _Float16 ghl[DD * GHLP7];        // 50K: [128][2*96 + pad]
    __shared__ float    bsum[2][4][256];        // 8K

    const int j8  = blockIdx.x;
    const int tid = threadIdx.x;
    const int w    = tid >> 6;
    const int lane = tid & 63;
    const int g    = lane >> 4;
    const int c    = lane & 15;
    const int dq   = w & 3;
    const int vv   = w >> 2;

    int bi = 0;   // barrier index == xh slot being written

    for (int p = 0; p < 2; ++p) {
        // ---- both variants' weight slices + biases into LDS (once per phase) ----
#pragma unroll
        for (int v2 = 0; v2 < 2; ++v2) {
            const _Float16* wsrc = Wr + ((size_t)(p * 2 + v2) * 8 + j8) * (3072 * 8);
            for (int idx = tid; idx < 3072; idx += 512)
                *(f16x8*)&wlds[v2][(size_t)idx * 8] = *(const f16x8*)(wsrc + (size_t)idx * 8);
        }
        {
            const float* bihc = p ? dcbih : ecbih;
            const float* bhhc = p ? dcbhh : ecbhh;
            const float* bihs = p ? dsbih : esbih;
            const float* bhhs = p ? dsbhh : esbhh;
            if (tid < 256) {
                bsum[0][0][tid] = bihc[tid]       + bhhc[tid];
                bsum[0][1][tid] = bihc[256 + tid] + bhhc[256 + tid];
                bsum[0][2][tid] = bihc[512 + tid];
                bsum[0][3][tid] = bhhc[512 + tid];
            } else {
                int t = tid - 256;
                bsum[1][0][t] = bihs[t]       + bhhs[t];
                bsum[1][1][t] = bihs[256 + t] + bhhs[256 + t];
                bsum[1][2][t] = bihs[512 + t];
                bsum[1][3][t] = bhhs[512 + t];
            }
        }
        __syncthreads();

        for (int st = 0; st < TT; ++st) {
            const bool first = (p == 0 && st == 0);
            const _Float16* hprev = xh + (size_t)(bi - 1) * (DD * HH);

            // ---- prefetch gi + h_old for this thread's 2 gate units ----
            f32x4 gpr[2][3];
            float hold[2][4];
            bool  eu[2];
#pragma unroll
            for (int uu = 0; uu < 2; ++uu) {
                const int u = tid + uu * 512;
                const int d = u >> 3, jl = (u & 7) * 4;
                const int jg_ = j8 * 32 + jl;
                const bool e = ecan[st * DD + d] != 0;
                eu[uu] = e;
                const float* gp = gi + (size_t)(st * DD + d) * 3072 + p * 1536
                                + (e ? 0 : 768) + jg_;
                gpr[uu][0] = *(const f32x4*)gp;
                gpr[uu][1] = *(const f32x4*)(gp + HH);
                gpr[uu][2] = *(const f32x4*)(gp + 2 * HH);
                if (first) {
                    const float* hp = enc_init + (size_t)d * HH + jg_;
                    hold[uu][0] = hp[0]; hold[uu][1] = hp[1];
                    hold[uu][2] = hp[2]; hold[uu][3] = hp[3];
                } else {
                    union { unsigned long long u64; _Float16 h[4]; } hu;
                    hu.u64 = *(const unsigned long long*)(hprev + (size_t)d * HH + jg_);
#pragma unroll
                    for (int m = 0; m < 4; ++m) hold[uu][m] = (float)hu.h[m];
                }
            }

            // ---- MFMA: A-frags straight from hprev global; B from LDS ----
            f32x4 acc[2][6];
#pragma unroll
            for (int a2 = 0; a2 < 2; ++a2)
#pragma unroll
                for (int b2 = 0; b2 < 6; ++b2) acc[a2][b2] = (f32x4){0.f, 0.f, 0.f, 0.f};
            const int r0 = (dq * 2) * 16 + c;
            const int r1 = (dq * 2 + 1) * 16 + c;
#pragma unroll
            for (int ks = 0; ks < 8; ++ks) {
                f16x8 a0, a1;
                if (first) {
                    const float* s0 = enc_init + (size_t)r0 * HH + ks * 32 + g * 8;
                    const float* s1 = enc_init + (size_t)r1 * HH + ks * 32 + g * 8;
                    float4 v00 = *(const float4*)s0, v01 = *(const float4*)(s0 + 4);
                    float4 v10 = *(const float4*)s1, v11 = *(const float4*)(s1 + 4);
                    a0[0] = (_Float16)v00.x; a0[1] = (_Float16)v00.y;
                    a0[2] = (_Float16)v00.z; a0[3] = (_Float16)v00.w;
                    a0[4] = (_Float16)v01.x; a0[5] = (_Float16)v01.y;
                    a0[6] = (_Float16)v01.z; a0[7] = (_Float16)v01.w;
                    a1[0] = (_Float16)v10.x; a1[1] = (_Float16)v10.y;
                    a1[2] = (_Float16)v10.z; a1[3] = (_Float16)v10.w;
                    a1[4] = (_Float16)v11.x; a1[5] = (_Float16)v11.y;
                    a1[6] = (_Float16)v11.z; a1[7] = (_Float16)v11.w;
                } else {
                    a0 = *(const f16x8*)(hprev + (size_t)r0 * HH + ks * 32 + g * 8);
                    a1 = *(const f16x8*)(hprev + (size_t)r1 * HH + ks * 32 + g * 8);
                }
#pragma unroll
                for (int tt = 0; tt < 6; ++tt) {
                    f16x8 bf = *(const f16x8*)&wlds[vv][((size_t)(tt * 8 + ks) * 64 + lane) * 8];
                    acc[0][tt] = __builtin_amdgcn_mfma_f32_16x16x32_f16(a0, bf, acc[0][tt], 0, 0, 0);
                    acc[1][tt] = __builtin_amdgcn_mfma_f32_16x16x32_f16(a1, bf, acc[1][tt], 0, 0, 0);
                }
            }

            // ---- acc -> ghl ----
#pragma unroll
            for (int dti = 0; dti < 2; ++dti) {
                const int rowb = (dq * 2 + dti) * 16 + 4 * g;
#pragma unroll
                for (int tt = 0; tt < 6; ++tt) {
                    const int jg2 = tt / 3, gt = tt % 3;
                    const int col = vv * 96 + gt * 32 + jg2 * 16 + c;
#pragma unroll
                    for (int rr = 0; rr < 4; ++rr)
                        ghl[(rowb + rr) * GHLP7 + col] = (_Float16)acc[dti][tt][rr];
                }
            }
            __syncthreads();

            // ---- gate (balanced, per-d variant select) ----
            _Float16* xcur = xh + (size_t)bi * (DD * HH);
#pragma unroll
            for (int uu = 0; uu < 2; ++uu) {
                const int u = tid + uu * 512;
                const int d = u >> 3, jl = (u & 7) * 4;
                const int jg_ = j8 * 32 + jl;
                const int vb = eu[uu] ? 0 : 1;
                f32x4 br  = *(const f32x4*)&bsum[vb][0][jg_];
                f32x4 bz  = *(const f32x4*)&bsum[vb][1][jg_];
                f32x4 bni = *(const f32x4*)&bsum[vb][2][jg_];
                f32x4 bnh = *(const f32x4*)&bsum[vb][3][jg_];
                const _Float16* gd = &ghl[d * GHLP7 + vb * 96];

                _Float16 hn[4];
                unsigned short ob[4];
#pragma unroll
                for (int m = 0; m < 4; ++m) {
                    float ghr = (float)gd[jl + m];
                    float ghz = (float)gd[32 + jl + m];
                    float ghn = (float)gd[64 + jl + m];
                    float rg = 1.f / (1.f + __expf(-(gpr[uu][0][m] + br[m] + ghr)));
                    float zg = 1.f / (1.f + __expf(-(gpr[uu][1][m] + bz[m] + ghz)));
                    float nn = tanhf(gpr[uu][2][m] + bni[m] + rg * (ghn + bnh[m]));
                    float hv = (1.f - zg) * nn + zg * hold[uu][m];
                    hn[m] = (_Float16)hv;
                    ob[m] = f2bf(hv);
                }
                __hip_atomic_store((unsigned long long*)(xcur + (size_t)d * HH + jg_),
                                   pack4h(hn[0], hn[1], hn[2], hn[3]),
                                   __ATOMIC_RELAXED, __HIP_MEMORY_SCOPE_AGENT);
                if (p) {
                    const int dt = d >> 4, lc = d & 15, ksx = jg_ >> 5, lg = (jg_ >> 3) & 3;
                    union { unsigned short s[4]; unsigned long long u; } ou;
                    ou.s[0] = ob[0]; ou.s[1] = ob[1]; ou.s[2] = ob[2]; ou.s[3] = ob[3];
                    size_t och = ((size_t)(st * 8 + dt) * 8 + ksx) * 64 + lg * 16 + lc;
                    *(unsigned long long*)((unsigned short*)outs_pk + och * 8 + (jg_ & 7)) = ou.u;
                }
            }
            __syncthreads();   // drains vmcnt before flag

            // ---- 8-flag barrier ----
            if (tid == 0)
                __hip_atomic_store(&flags[j8], bi + 1,
                                   __ATOMIC_RELAXED, __HIP_MEMORY_SCOPE_AGENT);
            if (tid < 64) {
                for (;;) {
                    int f = (tid < NBLK7)
                          ? __hip_atomic_load(&flags[tid], __ATOMIC_RELAXED, __HIP_MEMORY_SCOPE_AGENT)
                          : 0x7fffffff;
                    if (__all(f >= bi + 1)) break;
                    __builtin_amdgcn_s_sleep(1);
                }
            }
            __syncthreads();
            ++bi;
        }

        if (p == 0) {
            // ---- latent head, d-sharded: block handles 16 rows ----
            float* hlin = (float*)ghl;    // 16*256 f32 = 16KB (ghl reuse)
            const _Float16* hsrc = xh + (size_t)(bi - 1) * (DD * HH);  // slot 31
            for (int u2 = tid; u2 < 16 * HH; u2 += 512) {
                int du = u2 >> 8, k = u2 & 255;
                hlin[u2] = (float)hsrc[(size_t)(j8 * 16 + du) * HH + k];
            }
            __syncthreads();
            const int d16 = tid >> 5, q5 = tid & 31;
            const int dg = j8 * 16 + d16;
            f32x4 mean0, mean1, logv0, logv1;
            {
                f32x4 sm0 = {0,0,0,0}, sm1 = {0,0,0,0}, sl0 = {0,0,0,0}, sl1 = {0,0,0,0};
                const float* hl = hlin + d16 * HH;
                for (int k = 0; k < HH; ++k) {
                    float hv = hl[k];
                    const f32x4* wm = (const f32x4*)(WmT + (size_t)k * 256 + q5 * 8);
                    const f32x4* wl = (const f32x4*)(WlT + (size_t)k * 256 + q5 * 8);
                    sm0 += hv * wm[0]; sm1 += hv * wm[1];
                    sl0 += hv * wl[0]; sl1 += hv * wl[1];
                }
                mean0 = sm0 + *(const f32x4*)(b_mean + q5 * 8);
                mean1 = sm1 + *(const f32x4*)(b_mean + q5 * 8 + 4);
                logv0 = sl0 + *(const f32x4*)(b_logv + q5 * 8);
                logv1 = sl1 + *(const f32x4*)(b_logv + q5 * 8 + 4);
                *(f32x4*)(out_mean + (size_t)dg * ZZ + q5 * 8)     = mean0;
                *(f32x4*)(out_mean + (size_t)dg * ZZ + q5 * 8 + 4) = mean1;
                *(f32x4*)(out_logv + (size_t)dg * ZZ + q5 * 8)     = logv0;
                *(f32x4*)(out_logv + (size_t)dg * ZZ + q5 * 8 + 4) = logv1;
            }
            __syncthreads();   // all hlin reads done before overwrite with z
            {
                f32x4 ep0 = *(const f32x4*)(eps + (size_t)dg * ZZ + q5 * 8);
                f32x4 ep1 = *(const f32x4*)(eps + (size_t)dg * ZZ + q5 * 8 + 4);
                f32x4 zv0, zv1;
#pragma unroll
                for (int m = 0; m < 4; ++m) {
                    zv0[m] = ep0[m] * __expf(0.5f * logv0[m]) + mean0[m];
                    zv1[m] = ep1[m] * __expf(0.5f * logv1[m]) + mean1[m];
                }
                *(f32x4*)(out_z + (size_t)dg * ZZ + q5 * 8)     = zv0;
                *(f32x4*)(out_z + (size_t)dg * ZZ + q5 * 8 + 4) = zv1;
                *(f32x4*)(hlin + d16 * HH + q5 * 8)     = zv0;
                *(f32x4*)(hlin + d16 * HH + q5 * 8 + 4) = zv1;
            }
            __syncthreads();
            {
                f32x4 s0 = {0,0,0,0}, s1 = {0,0,0,0};
                const float* zl = hlin + d16 * HH;
                for (int k = 0; k < ZZ; ++k) {
                    float zv = zl[k];
                    const f32x4* wh = (const f32x4*)(WhT + (size_t)k * 256 + q5 * 8);
                    s0 += zv * wh[0]; s1 += zv * wh[1];
                }
                f32x4 h0a = s0 + *(const f32x4*)(b_l2h + q5 * 8);
                f32x4 h0b = s1 + *(const f32x4*)(b_l2h + q5 * 8 + 4);
                _Float16* xc = xh + (size_t)bi * (DD * HH) + (size_t)dg * HH + q5 * 8;
                __hip_atomic_store((unsigned long long*)xc,
                                   pack4h((_Float16)h0a[0], (_Float16)h0a[1],
                                          (_Float16)h0a[2], (_Float16)h0a[3]),
                                   __ATOMIC_RELAXED, __HIP_MEMORY_SCOPE_AGENT);
                __hip_atomic_store((unsigned long long*)(xc + 4),
                                   pack4h((_Float16)h0b[0], (_Float16)h0b[1],
                                          (_Float16)h0b[2], (_Float16)h0b[3]),
                                   __ATOMIC_RELAXED, __HIP_MEMORY_SCOPE_AGENT);
            }
            __syncthreads();
            if (tid == 0)
                __hip_atomic_store(&flags[j8], bi + 1,
                                   __ATOMIC_RELAXED, __HIP_MEMORY_SCOPE_AGENT);
            if (tid < 64) {
                for (;;) {
                    int f = (tid < NBLK7)
                          ? __hip_atomic_load(&flags[tid], __ATOMIC_RELAXED, __HIP_MEMORY_SCOPE_AGENT)
                          : 0x7fffffff;
                    if (__all(f >= bi + 1)) break;
                    __builtin_amdgcn_s_sleep(1);
                }
            }
            __syncthreads();
            ++bi;
        }
    }
}

// ---------------- per-row logsumexp merge (one wave per row, nt <= 64) ----------------
__global__ __launch_bounds__(64) void lse_reduce(
    const float* __restrict__ pm, const float* __restrict__ ps,
    float* __restrict__ lse, int nt)
{
    int row = blockIdx.x;
    int l = threadIdx.x;
    float m = (l < nt) ? pm[(size_t)row * nt + l] : -3.0e38f;
    float s = (l < nt) ? ps[(size_t)row * nt + l] : 0.f;
    for (int mk = 1; mk <= 32; mk <<= 1) {
        float m2 = __shfl_xor(m, mk);
        float s2 = __shfl_xor(s, mk);
        float mn = fmaxf(m, m2);
        s = s * __expf(m - mn) + s2 * __expf(m2 - mn);
        m = mn;
    }
    if (l == 0) lse[row] = m + logf(s);
}

extern "C" void kernel_launch(void* const* d_in, const int* in_sizes, int n_in,
                              void* d_out, int out_size, void* d_ws, size_t ws_size,
                              hipStream_t stream)
{
    const int*           nodes     = (const int*)d_in[0];
    const unsigned char* edges_raw = (const unsigned char*)d_in[1];
    const float* emb    = (const float*)d_in[2];
    const float* ecWih  = (const float*)d_in[3];
    const float* ecWhh  = (const float*)d_in[4];
    const float* ecbih  = (const float*)d_in[5];
    const float* ecbhh  = (const float*)d_in[6];
    const float* esWih  = (const float*)d_in[7];
    const float* esWhh  = (const float*)d_in[8];
    const float* esbih  = (const float*)d_in[9];
    const float* esbhh  = (const float*)d_in[10];
    const float* dcWih  = (const float*)d_in[11];
    const float* dcWhh  = (const float*)d_in[12];
    const float* dcbih  = (const float*)d_in[13];
    const float* dcbhh  = (const float*)d_in[14];
    const float* dsWih  = (const float*)d_in[15];
    const float* dsWhh  = (const float*)d_in[16];
    const float* dsbih  = (const float*)d_in[17];
    const float* dsbhh  = (const float*)d_in[18];
    const float* W_mean = (const float*)d_in[19];
    const float* b_mean = (const float*)d_in[20];
    const float* W_logv = (const float*)d_in[21];
    const float* b_logv = (const float*)d_in[22];
    const float* W_l2h  = (const float*)d_in[23];
    const float* b_l2h  = (const float*)d_in[24];
    const float* W_out  = (const float*)d_in[25];
    const float* b_out  = (const float*)d_in[26];
    const float* enc_init = (const float*)d_in[27];
    const float* eps    = (const float*)d_in[28];

    float* out      = (float*)d_out;
    float* out_mean = out + (size_t)TT * DD * VV;
    float* out_logv = out_mean + DD * ZZ;
    float* out_z    = out_logv + DD * ZZ;
    float* gi       = out;                  // scratch in logits region: [4096][3072]

    char* ws = (char*)d_ws;
    __hip_bfloat16* outs_pk = (__hip_bfloat16*)(ws + 0);         // 2MB
    __hip_bfloat16* Ap      = (__hip_bfloat16*)(ws + 2097152);   // 2MB
    __hip_bfloat16* Wp      = (__hip_bfloat16*)(ws + 4194304);   // 16.4MB
    __hip_bfloat16* Bp_all  = (__hip_bfloat16*)(ws + 20971520);  // 1.5MB
    _Float16*       Wr      = (_Float16*)(ws + 22544384);        // 1.5MB rnn-frag Whh x4
    float*          WmT     = (float*)(ws + 24117248);           // 256KB
    float*          WlT     = (float*)(ws + 24379392);           // 256KB
    float*          WhT     = (float*)(ws + 24641536);           // 256KB
    float*          pm      = (float*)(ws + 24903680);           // 800KB
    float*          ps      = (float*)(ws + 25722880);           // 800KB
    float*          lse     = (float*)(ws + 26542080);           // 16KB
    unsigned char*  ecan    = (unsigned char*)(ws + 26558464);   // 4KB
    _Float16*       xh      = (_Float16*)(ws + 26562560);        // 65 x 64KB
    int*            flags   = (int*)(ws + 30822400);             // 64B

    hipMemsetAsync(flags, 0, 64, stream);

    edge_canon_k<<<1, 256, 0, stream>>>(edges_raw, ecan);
    pack_frag<<<4000, 256, 0, stream>>>(W_out, Wp, 2000 * 8 * 64);
    pack_frag<<<96, 256, 0, stream>>>(ecWih, Bp_all + 0 * (size_t)48 * 4096, 48 * 8 * 64);
    pack_frag<<<96, 256, 0, stream>>>(esWih, Bp_all + 1 * (size_t)48 * 4096, 48 * 8 * 64);
    pack_frag<<<96, 256, 0, stream>>>(dcWih, Bp_all + 2 * (size_t)48 * 4096, 48 * 8 * 64);
    pack_frag<<<96, 256, 0, stream>>>(dsWih, Bp_all + 3 * (size_t)48 * 4096, 48 * 8 * 64);
    pack_wrnn<<<96, 256, 0, stream>>>(ecWhh, Wr + 0 * (size_t)24576 * 8);
    pack_wrnn<<<96, 256, 0, stream>>>(esWhh, Wr + 1 * (size_t)24576 * 8);
    pack_wrnn<<<96, 256, 0, stream>>>(dcWhh, Wr + 2 * (size_t)24576 * 8);
    pack_wrnn<<<96, 256, 0, stream>>>(dsWhh, Wr + 3 * (size_t)24576 * 8);
    pack_lat_t<<<256, 256, 0, stream>>>(W_mean, WmT);
    pack_lat_t<<<256, 256, 0, stream>>>(W_logv, WlT);
    pack_lat_t<<<256, 256, 0, stream>>>(W_l2h, WhT);
    gather_pack<<<512, 256, 0, stream>>>(nodes, emb, Ap);

    // gi[4096][3072] = emb-gather x [all 4 W_ih]^T  (into d_out scratch)
    gemm_rs<true, false, false, false><<<dim3(64, 6), 256, 0, stream>>>(
        Ap, Bp_all, 3072, 8, 6, nullptr, nullptr, gi, nullptr, nullptr);

    // fused recurrence: encoder -> latent -> h0 -> decoder (writes packed outs)
    rnn_fused7<<<NBLK7, 512, 0, stream>>>(
        ecan, gi, Wr,
        ecbih, ecbhh, esbih, esbhh, dcbih, dcbhh, dsbih, dsbhh,
        WmT, WlT, WhT, b_mean, b_logv, b_l2h,
        enc_init, eps, out_mean, out_logv, out_z, outs_pk, xh, flags);

    // pass A: LSE partials only (no C write)
    gemm_rs<false, true, true, false><<<dim3(64, NTL), 256, 0, stream>>>(
        outs_pk, Wp, VV, 10, NTL, b_out, nullptr, nullptr, pm, ps);
    lse_reduce<<<4096, 64, 0, stream>>>(pm, ps, lse, NTL);
    // pass B: recompute, write logp = logits - lse
    gemm_rs<true, true, false, true><<<dim3(64, NTL), 256, 0, stream>>>(
        outs_pk, Wp, VV, 10, NTL, b_out, lse, out, nullptr, nullptr);
}